// Round 1
// baseline (2889.958 us; speedup 1.0000x reference)
//
#include <hip/hip_runtime.h>
#include <hip/hip_bf16.h>
#include <stdint.h>

// Problem: CGAE graph deconvolution, N=16384, NFEAT=128, NHID=64, NOUT=128.
// z_ori/z_aug = fadj @ (feat/feat_a @ W1); xhat_* = fadj @ (z_* @ W2).
// Strategy: big GEMMs via 3-term split-bf16 MFMA emulation of fp32
// (A=Ah+Al, B=Bh+Bl; C ≈ Ah·Bh + Ah·Bl + Al·Bh, err ~1e-5 rel).
//
// ws layout (bytes), total 56 MiB:
//   [0,4M)    S1^T hi  [128][16384] bf16
//   [4M,8M)   S1^T lo
//   [8M,16M)  S2^T hi  [256][16384] bf16
//   [16M,24M) S2^T lo
//   [24M,56M) fp32 partials (K-split): max 4*16384*128*4 = 2*16384*256*4 = 32M

#define N_ROWS 16384
#define NFEAT 128
#define NHID 64
#define NOUT 128

typedef unsigned short u16;
typedef __attribute__((ext_vector_type(8))) short short8;
typedef __attribute__((ext_vector_type(4))) float f32x4;

#define WS_S1HI 0
#define WS_S1LO (4u << 20)
#define WS_S2HI (8u << 20)
#define WS_S2LO (16u << 20)
#define WS_PART (24u << 20)

// split one fp32 into hi/lo bf16 (truncation; lo = exact residual truncated)
__device__ __forceinline__ void split1(float f, u16& h, u16& l) {
    uint32_t u = __float_as_uint(f);
    h = (u16)(u >> 16);
    float lf = f - __uint_as_float(u & 0xFFFF0000u);
    l = (u16)(__float_as_uint(lf) >> 16);
}

// split 8 fp32 (two uint4) into packed hi/lo bf16x8 (uint4 each)
__device__ __forceinline__ void split_pack8(const uint4 a, const uint4 b,
                                            uint4& hp, uint4& lp) {
    uint32_t u[8] = {a.x, a.y, a.z, a.w, b.x, b.y, b.z, b.w};
    uint32_t h[8], l[8];
#pragma unroll
    for (int i = 0; i < 8; ++i) {
        uint32_t hu = u[i] & 0xFFFF0000u;
        float lf = __uint_as_float(u[i]) - __uint_as_float(hu);
        h[i] = u[i] >> 16;
        l[i] = __float_as_uint(lf) >> 16;
    }
    hp.x = h[0] | (h[1] << 16); hp.y = h[2] | (h[3] << 16);
    hp.z = h[4] | (h[5] << 16); hp.w = h[6] | (h[7] << 16);
    lp.x = l[0] | (l[1] << 16); lp.y = l[2] | (l[3] << 16);
    lp.z = l[4] | (l[5] << 16); lp.w = l[6] | (l[7] << 16);
}

// ---------------------------------------------------------------------------
// k_s1: S1 = feat|feat_a @ W1, written as S1^T hi/lo bf16 [128][N].
// grid (N/32, 2 streams), block 256.
// ---------------------------------------------------------------------------
__global__ __launch_bounds__(256) void k_s1(const float* __restrict__ feat,
                                            const float* __restrict__ feat_a,
                                            const float* __restrict__ W1,
                                            u16* __restrict__ s1hi,
                                            u16* __restrict__ s1lo) {
    const int s = blockIdx.y;
    const int r0 = blockIdx.x * 32;
    const float* X = s ? feat_a : feat;
    __shared__ float Ws[NFEAT * NHID];  // 32 KB
    __shared__ float Xs[32 * NFEAT];    // 16 KB
    const int t = threadIdx.x;
    {
        const float4* src = (const float4*)W1;
        float4* dst = (float4*)Ws;
#pragma unroll
        for (int i = 0; i < 8; ++i) dst[t + 256 * i] = src[t + 256 * i];
    }
    {
        const float4* src = (const float4*)(X + (size_t)r0 * NFEAT);
        float4* dst = (float4*)Xs;
#pragma unroll
        for (int i = 0; i < 4; ++i) dst[t + 256 * i] = src[t + 256 * i];
    }
    __syncthreads();
    const int tr = t >> 5, tc = t & 31;  // rows tr*4+[0,4), cols tc*2+[0,2)
    float acc[4][2] = {};
#pragma unroll 4
    for (int k = 0; k < NFEAT; ++k) {
        float b0 = Ws[k * NHID + tc * 2];
        float b1 = Ws[k * NHID + tc * 2 + 1];
#pragma unroll
        for (int i = 0; i < 4; ++i) {
            float a = Xs[(tr * 4 + i) * NFEAT + k];
            acc[i][0] += a * b0;
            acc[i][1] += a * b1;
        }
    }
#pragma unroll
    for (int j = 0; j < 2; ++j) {
        int cg = s * 64 + tc * 2 + j;
        u16 h[4], l[4];
#pragma unroll
        for (int i = 0; i < 4; ++i) split1(acc[i][j], h[i], l[i]);
        uint2 hp, lp;
        hp.x = (uint32_t)h[0] | ((uint32_t)h[1] << 16);
        hp.y = (uint32_t)h[2] | ((uint32_t)h[3] << 16);
        lp.x = (uint32_t)l[0] | ((uint32_t)l[1] << 16);
        lp.y = (uint32_t)l[2] | ((uint32_t)l[3] << 16);
        *(uint2*)&s1hi[(size_t)cg * N_ROWS + r0 + tr * 4] = hp;
        *(uint2*)&s1lo[(size_t)cg * N_ROWS + r0 + tr * 4] = lp;
    }
}

// ---------------------------------------------------------------------------
// k_s2: z = sum of 4 partials (written to d_out), S2 = z @ W2 as S2^T hi/lo.
// grid (N/32, 2 streams), block 256.
// ---------------------------------------------------------------------------
__global__ __launch_bounds__(256) void k_s2(const float* __restrict__ part,
                                            const float* __restrict__ W2,
                                            float* __restrict__ dz,
                                            u16* __restrict__ s2hi,
                                            u16* __restrict__ s2lo) {
    const int s = blockIdx.y;
    const int r0 = blockIdx.x * 32;
    __shared__ float Ws[NHID * NOUT];  // 32 KB
    __shared__ float Zs[32 * NHID];    // 8 KB
    const int t = threadIdx.x;
    {
        const float4* src = (const float4*)W2;
        float4* dst = (float4*)Ws;
#pragma unroll
        for (int i = 0; i < 8; ++i) dst[t + 256 * i] = src[t + 256 * i];
    }
    {
        const size_t pstride = (size_t)N_ROWS * 128;
#pragma unroll
        for (int i = 0; i < 8; ++i) {
            int e = t + 256 * i;  // 0..2047
            int row = e >> 6, c = e & 63;
            size_t gi = (size_t)(r0 + row) * 128 + s * 64 + c;
            float v = part[gi] + part[gi + pstride] + part[gi + 2 * pstride] +
                      part[gi + 3 * pstride];
            Zs[row * NHID + c] = v;
            dz[(size_t)s * N_ROWS * NHID + (size_t)(r0 + row) * NHID + c] = v;
        }
    }
    __syncthreads();
    const int tr = t >> 5, tc = t & 31;  // rows tr*4+[0,4), cols tc*4+[0,4)
    float acc[4][4] = {};
#pragma unroll 4
    for (int k = 0; k < NHID; ++k) {
        float4 b = *(const float4*)&Ws[k * NOUT + tc * 4];
#pragma unroll
        for (int i = 0; i < 4; ++i) {
            float a = Zs[(tr * 4 + i) * NHID + k];
            acc[i][0] += a * b.x; acc[i][1] += a * b.y;
            acc[i][2] += a * b.z; acc[i][3] += a * b.w;
        }
    }
#pragma unroll
    for (int j = 0; j < 4; ++j) {
        int cg = s * 128 + tc * 4 + j;
        u16 h[4], l[4];
#pragma unroll
        for (int i = 0; i < 4; ++i) split1(acc[i][j], h[i], l[i]);
        uint2 hp, lp;
        hp.x = (uint32_t)h[0] | ((uint32_t)h[1] << 16);
        hp.y = (uint32_t)h[2] | ((uint32_t)h[3] << 16);
        lp.x = (uint32_t)l[0] | ((uint32_t)l[1] << 16);
        lp.y = (uint32_t)l[2] | ((uint32_t)l[3] << 16);
        *(uint2*)&s2hi[(size_t)cg * N_ROWS + r0 + tr * 4] = hp;
        *(uint2*)&s2lo[(size_t)cg * N_ROWS + r0 + tr * 4] = lp;
    }
}

// ---------------------------------------------------------------------------
// big_gemm: part[kz] = fadj[r0:r0+128, kz-slice] @ S[kz-slice, c0:c0+128]
// A (fadj) fp32 reg-staged + split to hi/lo bf16 in LDS; B^T pre-split bf16.
// 128x128 tile, 4 waves (2x2), wave-tile 64x64, 16x16x32 bf16 MFMA, 3 terms.
// LDS tiles [128 rows][4 chunks of 16B] with chunk-XOR swizzle c^((r>>1)&3).
// grid (mtiles*ctiles, 1, ksplit), block 256.
// ---------------------------------------------------------------------------
__global__ __launch_bounds__(256, 2) void big_gemm(
    const float* __restrict__ fadj, const u16* __restrict__ bthi,
    const u16* __restrict__ btlo, float* __restrict__ part, int ctiles,
    int klen) {
    const int tid = threadIdx.x;
    const int mt = (int)blockIdx.x / ctiles;
    const int ct = (int)blockIdx.x % ctiles;
    const int kz = blockIdx.z;
    const int Ftot = ctiles * 128;
    const int r0 = mt * 128;
    const int c0 = ct * 128;
    const long kbase = (long)kz * klen;

    __shared__ uint4 lds4[4 * 512];  // Ah, Al, Bh, Bl : each 128 rows x 4 chunks
    uint4* Ah = lds4;
    uint4* Al = lds4 + 512;
    uint4* Bh = lds4 + 1024;
    uint4* Bl = lds4 + 1536;
    const short8* Ah8 = (const short8*)Ah;
    const short8* Al8 = (const short8*)Al;
    const short8* Bh8 = (const short8*)Bh;
    const short8* Bl8 = (const short8*)Bl;

    f32x4 acc[4][4];
#pragma unroll
    for (int m = 0; m < 4; ++m)
#pragma unroll
        for (int n = 0; n < 4; ++n) acc[m][n] = (f32x4){0.f, 0.f, 0.f, 0.f};

    const int w = tid >> 6, lane = tid & 63;
    const int wr = w >> 1, wc = w & 1;
    const int lrow = lane & 15, g = lane >> 4;

    const bool isA = tid < 128;
    const int srow = isA ? tid : tid - 128;
    const uint4* gA = (const uint4*)(fadj + (size_t)(r0 + srow) * N_ROWS);
    const uint4* gBh = (const uint4*)(bthi + (size_t)(c0 + srow) * N_ROWS);
    const uint4* gBl = (const uint4*)(btlo + (size_t)(c0 + srow) * N_ROWS);

    uint4 pre[8];

    auto load_tile = [&](long k) {
        if (isA) {
            const long b = k >> 2;  // fp32 -> uint4 index
#pragma unroll
            for (int i = 0; i < 8; ++i) pre[i] = gA[b + i];
        } else {
            const long b = k >> 3;  // bf16 -> uint4 index
#pragma unroll
            for (int i = 0; i < 4; ++i) pre[i] = gBh[b + i];
#pragma unroll
            for (int i = 0; i < 4; ++i) pre[4 + i] = gBl[b + i];
        }
    };

    auto stage = [&]() {
        const int r = srow;
        const int sw = (r >> 1) & 3;
        if (isA) {
#pragma unroll
            for (int c = 0; c < 4; ++c) {
                uint4 hp, lp;
                split_pack8(pre[2 * c], pre[2 * c + 1], hp, lp);
                Ah[r * 4 + (c ^ sw)] = hp;
                Al[r * 4 + (c ^ sw)] = lp;
            }
        } else {
#pragma unroll
            for (int c = 0; c < 4; ++c) {
                Bh[r * 4 + (c ^ sw)] = pre[c];
                Bl[r * 4 + (c ^ sw)] = pre[4 + c];
            }
        }
    };

    load_tile(kbase);
    const int nk = klen >> 5;
    for (int kt = 0; kt < nk; ++kt) {
        __syncthreads();  // previous tile's reads complete
        stage();
        if (kt + 1 < nk) load_tile(kbase + (long)(kt + 1) * 32);
        __syncthreads();  // staged tile visible

        short8 ah[4], al[4];
#pragma unroll
        for (int m = 0; m < 4; ++m) {
            int r = wr * 64 + m * 16 + lrow;
            int idx = r * 4 + (g ^ ((r >> 1) & 3));
            ah[m] = Ah8[idx];
            al[m] = Al8[idx];
        }
#pragma unroll
        for (int n = 0; n < 4; ++n) {
            int r = wc * 64 + n * 16 + lrow;
            int idx = r * 4 + (g ^ ((r >> 1) & 3));
            short8 bh = Bh8[idx];
            short8 bl = Bl8[idx];
#pragma unroll
            for (int m = 0; m < 4; ++m) {
                acc[m][n] = __builtin_amdgcn_mfma_f32_16x16x32_bf16(ah[m], bh, acc[m][n], 0, 0, 0);
                acc[m][n] = __builtin_amdgcn_mfma_f32_16x16x32_bf16(ah[m], bl, acc[m][n], 0, 0, 0);
                acc[m][n] = __builtin_amdgcn_mfma_f32_16x16x32_bf16(al[m], bh, acc[m][n], 0, 0, 0);
            }
        }
    }

    // epilogue: C/D layout col=lane&15, row=(lane>>4)*4+j (m89-verified)
    const size_t pbase = (size_t)kz * N_ROWS * Ftot;
#pragma unroll
    for (int m = 0; m < 4; ++m) {
        int row = wr * 64 + m * 16 + (lane >> 4) * 4;
#pragma unroll
        for (int n = 0; n < 4; ++n) {
            int col = wc * 64 + n * 16 + (lane & 15);
#pragma unroll
            for (int j = 0; j < 4; ++j) {
                part[pbase + (size_t)(r0 + row + j) * Ftot + (c0 + col)] =
                    acc[m][n][j];
            }
        }
    }
}

// ---------------------------------------------------------------------------
// k_red: xhat = part[0] + part[1]; split cols 0:128 -> ori, 128:256 -> aug.
// ---------------------------------------------------------------------------
__global__ __launch_bounds__(256) void k_red(const float* __restrict__ part,
                                             float* __restrict__ xo,
                                             float* __restrict__ xa) {
    const size_t total = (size_t)N_ROWS * 256 / 4;  // float4 count
    size_t i = (size_t)blockIdx.x * blockDim.x + threadIdx.x;
    for (; i < total; i += (size_t)gridDim.x * blockDim.x) {
        const float4 a = ((const float4*)part)[i];
        const float4 b = ((const float4*)part)[i + total];
        float4 v;
        v.x = a.x + b.x; v.y = a.y + b.y; v.z = a.z + b.z; v.w = a.w + b.w;
        size_t e = i * 4;
        int c = (int)(e & 255);
        size_t row = e >> 8;
        float* dst = (c < 128) ? (xo + row * 128 + c) : (xa + row * 128 + (c - 128));
        *(float4*)dst = v;
    }
}

extern "C" void kernel_launch(void* const* d_in, const int* in_sizes, int n_in,
                              void* d_out, int out_size, void* d_ws,
                              size_t ws_size, hipStream_t stream) {
    const float* feat = (const float*)d_in[0];
    const float* feat_a = (const float*)d_in[1];
    const float* fadj = (const float*)d_in[2];
    const float* W1 = (const float*)d_in[3];
    const float* W2 = (const float*)d_in[4];
    float* out = (float*)d_out;
    char* ws = (char*)d_ws;

    u16* s1hi = (u16*)(ws + WS_S1HI);
    u16* s1lo = (u16*)(ws + WS_S1LO);
    u16* s2hi = (u16*)(ws + WS_S2HI);
    u16* s2lo = (u16*)(ws + WS_S2LO);
    float* part = (float*)(ws + WS_PART);

    // d_out layout: z_ori[N*64] | z_aug[N*64] | xhat_ori[N*128] | xhat_aug[N*128]
    float* z_out = out;                        // both streams, s-indexed inside
    float* xo = out + 2 * (size_t)N_ROWS * NHID;
    float* xa = xo + (size_t)N_ROWS * NOUT;

    // 1) S1^T hi/lo
    hipLaunchKernelGGL(k_s1, dim3(N_ROWS / 32, 2), dim3(256), 0, stream, feat,
                       feat_a, W1, s1hi, s1lo);
    // 2) partials = fadj @ S1 (F=128, K-split 4)
    hipLaunchKernelGGL(big_gemm, dim3(128, 1, 4), dim3(256), 0, stream, fadj,
                       s1hi, s1lo, part, 1, 4096);
    // 3) z -> d_out, S2^T hi/lo
    hipLaunchKernelGGL(k_s2, dim3(N_ROWS / 32, 2), dim3(256), 0, stream, part,
                       W2, z_out, s2hi, s2lo);
    // 4) partials = fadj @ S2 (F=256 via 2 col-tiles, K-split 2)
    hipLaunchKernelGGL(big_gemm, dim3(256, 1, 2), dim3(256), 0, stream, fadj,
                       s2hi, s2lo, part, 2, 8192);
    // 5) xhat = part[0] + part[1] -> d_out
    hipLaunchKernelGGL(k_red, dim3(2048), dim3(256), 0, stream, part, xo, xa);
}